// Round 1
// baseline (220.892 us; speedup 1.0000x reference)
//
#include <hip/hip_runtime.h>

#define NCOLS 1024  // N is fixed at 1024 per the reference setup

// One block per row. 256 threads x float4 = 1024 floats, held in registers
// so each input element is read from HBM exactly once.
__global__ __launch_bounds__(256) void Normalizer_row_kernel(
    const float* __restrict__ a0, const float* __restrict__ a1,
    float* __restrict__ out, int rows_per_input) {
    int row = blockIdx.x;
    const float* src;
    float* dst;
    if (row < rows_per_input) {
        src = a0 + (size_t)row * NCOLS;
        dst = out + (size_t)row * NCOLS;
    } else {
        int r = row - rows_per_input;
        src = a1 + (size_t)r * NCOLS;
        dst = out + (size_t)rows_per_input * NCOLS + (size_t)r * NCOLS;
    }

    const int tid = threadIdx.x;
    float4 v = reinterpret_cast<const float4*>(src)[tid];

    // Pairwise partial sum, then wave-64 shuffle tree.
    float s = (v.x + v.y) + (v.z + v.w);
#pragma unroll
    for (int off = 32; off > 0; off >>= 1)
        s += __shfl_down(s, off, 64);

    __shared__ float ws[4];
    const int lane = tid & 63;
    const int wave = tid >> 6;
    if (lane == 0) ws[wave] = s;
    __syncthreads();

    float deg = (ws[0] + ws[1]) + (ws[2] + ws[3]);
    float inv = 1.0f / deg;
    if (!isfinite(inv)) inv = 0.0f;  // nan/inf -> 0 per reference

    float4 o;
    o.x = v.x * inv;
    o.y = v.y * inv;
    o.z = v.z * inv;
    o.w = v.w * inv;
    reinterpret_cast<float4*>(dst)[tid] = o;
}

extern "C" void kernel_launch(void* const* d_in, const int* in_sizes, int n_in,
                              void* d_out, int out_size, void* d_ws, size_t ws_size,
                              hipStream_t stream) {
    const float* a0 = (const float*)d_in[0];
    const float* a1 = (const float*)d_in[1];
    float* out = (float*)d_out;

    const int rows_per_input = in_sizes[0] / NCOLS;  // 16 * 1024 = 16384
    const int total_rows = 2 * rows_per_input;       // both inputs in one launch

    Normalizer_row_kernel<<<total_rows, 256, 0, stream>>>(a0, a1, out, rows_per_input);
}

// Round 3
// 219.061 us; speedup vs baseline: 1.0084x; 1.0084x over previous
//
#include <hip/hip_runtime.h>

#define NCOLS 1024  // N fixed at 1024 per reference setup

// Native clang vector type — accepted by __builtin_nontemporal_load/store
// (HIP's float4 is a class and is rejected).
typedef float vfloat4 __attribute__((ext_vector_type(4)));

// One WAVE per row: 64 lanes x 4 vfloat4 = 1024 floats held in registers.
// Pure shuffle-butterfly reduction -- no LDS, no __syncthreads.
// Nontemporal loads/stores: data is streamed once, don't pollute L2/L3.
__global__ __launch_bounds__(256) void Normalizer_row_kernel(
    const float* __restrict__ a0, const float* __restrict__ a1,
    float* __restrict__ out, int rows_per_input) {
    const int tid  = threadIdx.x;
    const int lane = tid & 63;
    const int wave = tid >> 6;
    const int row  = blockIdx.x * 4 + wave;   // global row in [0, 2*rows_per_input)

    // Output is the two normalized tensors concatenated: dst is simply row-major.
    const float* src = (row < rows_per_input)
        ? a0 + (size_t)row * NCOLS
        : a1 + (size_t)(row - rows_per_input) * NCOLS;
    float* dst = out + (size_t)row * NCOLS;

    const vfloat4* src4 = reinterpret_cast<const vfloat4*>(src);
    vfloat4* dst4 = reinterpret_cast<vfloat4*>(dst);

    // 4 independent 16B loads per lane (ILP), perfectly coalesced 1 KiB/wave each.
    vfloat4 v0 = __builtin_nontemporal_load(&src4[lane]);
    vfloat4 v1 = __builtin_nontemporal_load(&src4[lane + 64]);
    vfloat4 v2 = __builtin_nontemporal_load(&src4[lane + 128]);
    vfloat4 v3 = __builtin_nontemporal_load(&src4[lane + 192]);

    // Pairwise per-lane partial sum (16 values), then 6-step butterfly so
    // every lane ends with the full row sum (no broadcast needed).
    float s = ((v0.x + v0.y) + (v0.z + v0.w)) + ((v1.x + v1.y) + (v1.z + v1.w))
            + ((v2.x + v2.y) + (v2.z + v2.w)) + ((v3.x + v3.y) + (v3.z + v3.w));
#pragma unroll
    for (int off = 32; off > 0; off >>= 1)
        s += __shfl_xor(s, off, 64);

    float inv = 1.0f / s;
    if (!isfinite(inv)) inv = 0.0f;  // nan/inf -> 0 per reference

    v0 *= inv;
    v1 *= inv;
    v2 *= inv;
    v3 *= inv;

    __builtin_nontemporal_store(v0, &dst4[lane]);
    __builtin_nontemporal_store(v1, &dst4[lane + 64]);
    __builtin_nontemporal_store(v2, &dst4[lane + 128]);
    __builtin_nontemporal_store(v3, &dst4[lane + 192]);
}

extern "C" void kernel_launch(void* const* d_in, const int* in_sizes, int n_in,
                              void* d_out, int out_size, void* d_ws, size_t ws_size,
                              hipStream_t stream) {
    const float* a0 = (const float*)d_in[0];
    const float* a1 = (const float*)d_in[1];
    float* out = (float*)d_out;

    const int rows_per_input = in_sizes[0] / NCOLS;  // 16 * 1024 = 16384
    const int total_rows = 2 * rows_per_input;       // 32768
    const int blocks = total_rows / 4;               // 4 waves (rows) per block

    Normalizer_row_kernel<<<blocks, 256, 0, stream>>>(a0, a1, out, rows_per_input);
}